// Round 22
// baseline (1009.139 us; speedup 1.0000x reference)
//
#include <hip/hip_runtime.h>
#include <hip/hip_bf16.h>

typedef __bf16 bf16;
typedef __bf16 bf16x8 __attribute__((ext_vector_type(8)));
typedef __bf16 bf16x4 __attribute__((ext_vector_type(4)));
typedef float f32x4 __attribute__((ext_vector_type(4)));

#define T_SEQ 80
#define NB 256
#define NT 1024
#define U 1024
#define U3 3072

// ws byte offsets
#define WT_OFF   0ull                  // 3*3072*1024*2 = 18874368
#define WXT_OFF  18874368ull           // 3072*128*2    = 786432
#define XG_OFF   19660800ull           // 80*128*128*2  = 2621440
#define GX1_OFF  22282240ull           // 80*3072*128*2 = 62914560
#define H0B_OFF  85196800ull           // 81 * 128*1024*2 = 21233664 (deep buffers)
#define H1B_OFF  106430464ull          // 21233664
#define CNT_OFF  127664128ull          // barrier counters (2048 B)
#define WS_NEED  127666176ull

#define HBUF_ELEMS 131072ull           // 128*1024 bf16 per h buffer

// h buffers use a TILED layout so each wave's A-fragment load is ONE contiguous
// 1KB segment:  elem(row, col) at (row>>4)*16384 + (col>>5)*512 + (row&15)*32 + (col&31)

// LDS: 36 weight slots (3 matrices x 12 cols) of 1024 bf16, then Sx2, then red
#define LDS_SX2_OFF   73728                  // 36*1024*2
#define LDS_RED_OFF   (73728 + 12*132*4)     // after Sx2[12][132] f32 = 80064
#define LDS_BYTES     (LDS_RED_OFF + 64)     // = 80128

__device__ __forceinline__ float sigmoidf_(float x) { return 1.f / (1.f + __expf(-x)); }

__global__ void k_embed(const int* __restrict__ tok, const float* __restrict__ E,
                        bf16* __restrict__ Xg) {
  int idx = blockIdx.x * 256 + threadIdx.x;   // over 80*128*128, layout [t][b][k]
  int k = idx & 127;
  int bt = idx >> 7;
  int b = bt & 127;
  int t = bt >> 7;
  float v = 0.f;
  if (k < 100) v = E[(size_t)tok[b * 80 + t] * 100 + k];
  Xg[idx] = (bf16)v;
}

__global__ void k_trans(const float* __restrict__ Wh1, const float* __restrict__ Wx2,
                        const float* __restrict__ Wh2, bf16* __restrict__ WT) {
  __shared__ float tile[32][33];
  const float* src = (blockIdx.z == 0) ? Wh1 : (blockIdx.z == 1) ? Wx2 : Wh2;
  int cb = blockIdx.x * 32, kb = blockIdx.y * 32;
  int tx = threadIdx.x, ty = threadIdx.y;
  for (int i = ty; i < 32; i += 8) tile[i][tx] = src[(size_t)(kb + i) * U3 + cb + tx];
  __syncthreads();
  bf16* dst = WT + (size_t)blockIdx.z * U3 * U;  // [col][k] bf16
  for (int i = ty; i < 32; i += 8) dst[(size_t)(cb + i) * U + kb + tx] = (bf16)tile[tx][i];
}

__global__ void k_wxt(const float* __restrict__ Wx1, bf16* __restrict__ WXT) {
  __shared__ float tile[32][33];
  int cb = blockIdx.x * 32, kb = blockIdx.y * 32;
  int tx = threadIdx.x, ty = threadIdx.y;
  for (int i = ty; i < 32; i += 8) {
    int k = kb + i;
    tile[i][tx] = (k < 100) ? Wx1[(size_t)k * U3 + cb + tx] : 0.f;
  }
  __syncthreads();
  for (int i = ty; i < 32; i += 8) WXT[(size_t)(cb + i) * 128 + kb + tx] = (bf16)tile[tx][i];
}

// GX1[t][col][b] = (x_t @ Wx1 + bx1), bf16, col-major over batch
__global__ __launch_bounds__(256) void k_gx1(const bf16* __restrict__ Xg,
                                             const bf16* __restrict__ WXT,
                                             const float* __restrict__ bx1,
                                             bf16* __restrict__ GX1) {
  int mb = blockIdx.x * 64, nb = blockIdx.y * 64;
  int w = threadIdx.x >> 6, l = threadIdx.x & 63;
  int lr = l & 15, lq = l >> 4;
  int rowA = mb + w * 16 + lr;                 // m = t*128 + b
  int tA = rowA >> 7, bA = rowA & 127;
  const bf16* aptr = Xg + ((size_t)tA * 128 + bA) * 128 + lq * 8;
  f32x4 acc[4] = {};
  #pragma unroll
  for (int ks = 0; ks < 4; ++ks) {
    bf16x8 a = *(const bf16x8*)(aptr + ks * 32);
    #pragma unroll
    for (int nt = 0; nt < 4; ++nt) {
      int col = nb + nt * 16 + lr;
      bf16x8 b = *(const bf16x8*)(WXT + (size_t)col * 128 + ks * 32 + lq * 8);
      acc[nt] = __builtin_amdgcn_mfma_f32_16x16x32_bf16(a, b, acc[nt], 0, 0, 0);
    }
  }
  int m0 = mb + w * 16 + lq * 4;
  int t0 = m0 >> 7, b0 = m0 & 127;
  #pragma unroll
  for (int nt = 0; nt < 4; ++nt) {
    int col = nb + nt * 16 + lr;
    float bias = bx1[col];
    bf16x4 o;
    #pragma unroll
    for (int j = 0; j < 4; ++j) o[j] = (bf16)(acc[nt][j] + bias);
    *(bf16x4*)(GX1 + ((size_t)t0 * U3 + col) * 128 + b0) = o;
  }
}

// Weight slots: sid = mat*12 + s; s: 0-3 = z cols c0..c0+3, 4-7 = r, 8-11 = n.
// 16B-granule XOR-swizzled by s (12 distinct keys; mirror lanes re-read s-12 ->
// identical address -> LDS broadcast, conflict-free).
__device__ __forceinline__ bf16x8 ldsw(const bf16* Wlds, int mat, int scol, int k8) {
  return *(const bf16x8*)(Wlds + (((mat * 12 + scol) << 10) + ((k8 ^ scol) << 3)));
}

// Packed-pair h store: even/odd lane pair holds adjacent columns, same row.
// Agent-scope relaxed atomic store -> data lands at the coherence point (IF).
__device__ __forceinline__ void st_pair(bf16* dst_even, int lr, float h) {
  bf16 hb16 = (bf16)h;
  unsigned hb = (unsigned)__builtin_bit_cast(unsigned short, hb16);
  unsigned pb = (unsigned)__shfl_xor((int)hb, 1) & 0xffffu;
  if (!(lr & 1)) {
    unsigned v = hb | (pb << 16);
    __hip_atomic_store((unsigned*)dst_even, v, __ATOMIC_RELAXED, __HIP_MEMORY_SCOPE_AGENT);
  }
}

// Fence-free tree barrier, 256 blocks: 8 arrival lines x 32 blocks.
__device__ void gridbar(int* cnt, int i) {
  __syncthreads();
  if (threadIdx.x == 0) {
    int* gc   = cnt + (blockIdx.x & 7) * 32;   // 128B apart
    int* root = cnt + 256;
    int* go   = cnt + 288;
    int old = __hip_atomic_fetch_add(gc, 1, __ATOMIC_RELAXED, __HIP_MEMORY_SCOPE_AGENT);
    if (old == 32 * (i + 1) - 1) {             // group leader this iteration
      int r = __hip_atomic_fetch_add(root, 1, __ATOMIC_RELAXED, __HIP_MEMORY_SCOPE_AGENT);
      if (r == 8 * (i + 1) - 1)
        __hip_atomic_store(go, i + 1, __ATOMIC_RELAXED, __HIP_MEMORY_SCOPE_AGENT);
    }
    while (__hip_atomic_load(go, __ATOMIC_RELAXED, __HIP_MEMORY_SCOPE_AGENT) < i + 1)
      __builtin_amdgcn_s_sleep(4);
  }
  __syncthreads();
}

// NB=256 (ALL 256 CUs), 4 columns/block. One B-tile per matrix holds z+r+n
// (cols 0-3/4-7/8-11, 12-15 mirror z). Waves 0-7 = h0 (gh1 + gx2: 2 MFMA/step),
// waves 8-15 = h1 (gh2: 1 MFMA/step). 4 waves/SIMD; tiled h layout.
__global__ __launch_bounds__(NT, 1) void k_main(
    const bf16* __restrict__ WT, const bf16* __restrict__ GX1,
    bf16* __restrict__ h0b, bf16* __restrict__ h1b, int* __restrict__ cnt,
    const float* __restrict__ bh1, const float* __restrict__ bx2,
    const float* __restrict__ bh2, const float* __restrict__ Wf,
    const float* __restrict__ bfp, float* __restrict__ out) {
  extern __shared__ char lds[];
  bf16* Wlds = (bf16*)lds;
  float* Sx2 = (float*)(lds + LDS_SX2_OFF);   // [12][132] f32: gx2 handoff
  float* red = (float*)(lds + LDS_RED_OFF);   // 16 floats

  const int tid = threadIdx.x;
  const int w = tid >> 6, l = tid & 63;
  const int lr = l & 15, lq = l >> 4;
  const int c0 = blockIdx.x * 4;              // this block's h-column base (4 cols)
  const int koff = (blockIdx.x >> 3) & 31;    // XCD-local K-walk stagger
  const int scol = (lr < 12) ? lr : (lr - 12);

  // lane's global gate column: 0-3 z, 4-7 r, 8-11 n, 12-15 mirror z
  int col_g;
  if (lr < 4)       col_g = c0 + lr;
  else if (lr < 8)  col_g = U + c0 + (lr - 4);
  else if (lr < 12) col_g = 2 * U + c0 + (lr - 8);
  else              col_g = c0 + (lr - 12);

  // tiled-layout write offset (c0 mult of 4; lr<4 stays within the 32-col tile)
  const int wr_kq = (c0 >> 5) * 512 + (c0 & 31);

  // ---- stage 36 weight slots into LDS (bf16, k-contiguous, XOR-swizzled) ----
  for (int u = tid; u < 4608; u += NT) {      // 36 slots * 128 granules
    int chunk = u & 127;
    int sid = u >> 7;
    int mat = sid / 12, s = sid - mat * 12;
    int gcol = (s < 4) ? (c0 + s) : (s < 8) ? (U + c0 + s - 4) : (2 * U + c0 + s - 8);
    bf16x8 v = *(const bf16x8*)(WT + ((size_t)mat * U3 + gcol) * U + chunk * 8);
    *(bf16x8*)(Wlds + ((size_t)sid << 10) + ((chunk ^ s) << 3)) = v;
  }
  __syncthreads();

  // ---- per-lane biases ----
  const float b1c  = bh1[col_g];
  const float bx2c = bx2[col_g];
  const float bh2c = bh2[col_g];

  float hm[4];                                // fp32 master state slice (lr<4 lanes)
  #pragma unroll
  for (int q = 0; q < 4; ++q) hm[q] = 0.f;

  for (int i = 0; i <= T_SEQ; ++i) {
    // deep buffers: iter i reads h0b[i], h1b[i-1]; writes h0b[i+1], h1b[i].
    const bf16* h0r = h0b + (size_t)i * HBUF_ELEMS;
    const bf16* h1r = h1b + (size_t)(i > 0 ? i - 1 : 0) * HBUF_ELEMS;
    bf16* h0w = h0b + (size_t)(i + 1) * HBUF_ELEMS;
    bf16* h1w = h1b + (size_t)i * HBUF_ELEMS;

    f32x4 a3 = {};

    if (w < 8) {
      // ===== h0-waves: gh1 (zrn tile) + gx2 (zrn tile), shared A = H0[i-1] =====
      f32x4 a1 = {}, a2 = {};

      // GX1 gate load: one bf16x4 per lane at its column (includes bx1)
      bf16x4 g4 = {};
      if (i < T_SEQ) {
        const bf16* gx = GX1 + (size_t)i * U3 * 128;
        int r0 = w * 16 + lq * 4;
        g4 = *(const bf16x4*)(gx + (size_t)col_g * 128 + r0);
      }

      // tiled layout: wave w's A-panel is tile w; one contiguous 1KB read/step
      const bf16* abase = h0r + w * 16384 + lr * 32 + lq * 8;
      #pragma unroll 8
      for (int ks = 0; ks < 32; ++ks) {
        int kss = (ks + koff) & 31;            // XCD-local staggered K-walk
        bf16x8 A = *(const bf16x8*)(abase + kss * 512);
        int k8 = kss * 4 + lq;
        bf16x8 B1 = ldsw(Wlds, 0, scol, k8);
        bf16x8 B2 = ldsw(Wlds, 1, scol, k8);
        a1 = __builtin_amdgcn_mfma_f32_16x16x32_bf16(A, B1, a1, 0, 0, 0);
        a2 = __builtin_amdgcn_mfma_f32_16x16x32_bf16(A, B2, a2, 0, 0, 0);
      }
      // deposit gx2 (all 12 live columns) for the h1-waves
      {
        int r0 = w * 16 + lq * 4;
        if (lr < 12) *(f32x4*)(Sx2 + lr * 132 + r0) = a2;
      }
      // h0 update: H0[i] = GRU1(H0[i-1], x[i])
      if (i < T_SEQ) {
        f32x4 gf, p, q, sv;
        #pragma unroll
        for (int j = 0; j < 4; ++j) {
          gf[j] = (float)g4[j];
          p[j] = a1[j] + b1c;                  // n lanes: gh1n + bhn1
          q[j] = p[j] + gf[j];                 // z/r lanes: full preact
          sv[j] = sigmoidf_(q[j]);
        }
        f32x4 rv, gn, pn;
        #pragma unroll
        for (int j = 0; j < 4; ++j) {
          rv[j] = __shfl_xor(sv[j], 4);        // r-gate (col +4)
          gn[j] = __shfl_xor(gf[j], 8);        // gx1 n-part (col +8)
          pn[j] = __shfl_xor(p[j], 8);         // gh1 n-part (col +8)
        }
        if (lr < 4) {
          #pragma unroll
          for (int j = 0; j < 4; ++j) {
            float nn = tanhf(gn[j] + rv[j] * pn[j]);
            float z = sv[j];
            float h = z * hm[j] + (1.f - z) * nn;
            hm[j] = h;
            st_pair(h0w + w * 16384 + wr_kq + (lq * 4 + j) * 32 + (lr & ~1), lr, h);
          }
        }
      }
    } else if (i > 0) {
      // ===== h1-waves: gh2 = H1[i-2]@Wh2 (zrn tile) =====
      const bf16* abase = h1r + (w - 8) * 16384 + lr * 32 + lq * 8;
      #pragma unroll 8
      for (int ks = 0; ks < 32; ++ks) {
        int kss = (ks + koff) & 31;
        bf16x8 A = *(const bf16x8*)(abase + kss * 512);
        int k8 = kss * 4 + lq;
        bf16x8 B3 = ldsw(Wlds, 2, scol, k8);
        a3 = __builtin_amdgcn_mfma_f32_16x16x32_bf16(A, B3, a3, 0, 0, 0);
      }
    }
    __syncthreads();   // gx2 handoff visible to h1-waves
    if (w >= 8 && i > 0) {
      // h1 update: H1[i-1] = GRU2(H1[i-2], H0[i-1])
      int r0 = (w - 8) * 16 + lq * 4;
      f32x4 s2 = *(const f32x4*)(Sx2 + scol * 132 + r0);
      f32x4 q, p3, xn, sv;
      #pragma unroll
      for (int j = 0; j < 4; ++j) {
        q[j]  = a3[j] + bx2c + bh2c + s2[j];   // z/r lanes: full preact
        p3[j] = a3[j] + bh2c;                  // n lanes: gh2n + bhn2
        xn[j] = s2[j] + bx2c;                  // n lanes: gx2n + bxn2
        sv[j] = sigmoidf_(q[j]);
      }
      f32x4 rv, hn, xnn;
      #pragma unroll
      for (int j = 0; j < 4; ++j) {
        rv[j]  = __shfl_xor(sv[j], 4);
        hn[j]  = __shfl_xor(p3[j], 8);
        xnn[j] = __shfl_xor(xn[j], 8);
      }
      if (lr < 4) {
        #pragma unroll
        for (int j = 0; j < 4; ++j) {
          float nn = tanhf(xnn[j] + rv[j] * hn[j]);
          float z = sv[j];
          float h = z * hm[j] + (1.f - z) * nn;
          hm[j] = h;
          st_pair(h1w + (w - 8) * 16384 + wr_kq + (lq * 4 + j) * 32 + (lr & ~1), lr, h);
        }
      }
    }
    gridbar(cnt, i);
  }

  // ---- final dense head: out[b] = sigmoid(H1[79] . Wf + bf), blocks 0-127 ----
  if (blockIdx.x < 128) {
    const bf16* h1f = h1b + (size_t)T_SEQ * HBUF_ELEMS;
    const int b = blockIdx.x;
    float part = 0.f;
    if (tid < 256) {
      int k0 = tid * 4;
      const bf16* p = h1f + (b >> 4) * 16384 + (k0 >> 5) * 512 + (b & 15) * 32 + (k0 & 31);
      bf16x4 hv = *(const bf16x4*)p;
      #pragma unroll
      for (int j = 0; j < 4; ++j) part += (float)hv[j] * Wf[k0 + j];
    }
    #pragma unroll
    for (int off = 32; off > 0; off >>= 1) part += __shfl_down(part, off);
    if (l == 0) red[w] = part;
    __syncthreads();
    if (tid == 0) {
      float s = bfp[0];
      #pragma unroll
      for (int q = 0; q < 16; ++q) s += red[q];
      out[blockIdx.x] = sigmoidf_(s);
    }
  }
}

extern "C" void kernel_launch(void* const* d_in, const int* in_sizes, int n_in,
                              void* d_out, int out_size, void* d_ws, size_t ws_size,
                              hipStream_t stream) {
  if (ws_size < WS_NEED) return;  // workspace insufficient -> deliberate clean fail
  const int*   tok = (const int*)d_in[0];
  const float* E   = (const float*)d_in[1];
  const float* Wx1 = (const float*)d_in[2];
  const float* Wh1 = (const float*)d_in[3];
  const float* bx1 = (const float*)d_in[4];
  const float* bh1 = (const float*)d_in[5];
  const float* Wx2 = (const float*)d_in[6];
  const float* Wh2 = (const float*)d_in[7];
  const float* bx2 = (const float*)d_in[8];
  const float* bh2 = (const float*)d_in[9];
  const float* Wf  = (const float*)d_in[10];
  const float* bfp = (const float*)d_in[11];
  char* ws = (char*)d_ws;
  bf16* WT   = (bf16*)(ws + WT_OFF);
  bf16* WXT  = (bf16*)(ws + WXT_OFF);
  bf16* Xg   = (bf16*)(ws + XG_OFF);
  bf16* GX1  = (bf16*)(ws + GX1_OFF);
  bf16* h0b  = (bf16*)(ws + H0B_OFF);
  bf16* h1b  = (bf16*)(ws + H1B_OFF);
  int*  cnt  = (int*)(ws + CNT_OFF);

  // zero only what's read-before-write: h0b[0], h1b[0], counters
  hipMemsetAsync(ws + H0B_OFF, 0, 262144, stream);
  hipMemsetAsync(ws + H1B_OFF, 0, 262144, stream);
  hipMemsetAsync(ws + CNT_OFF, 0, 2048, stream);
  k_embed<<<dim3(5120), dim3(256), 0, stream>>>(tok, E, Xg);
  k_trans<<<dim3(96, 32, 3), dim3(32, 8), 0, stream>>>(Wh1, Wx2, Wh2, WT);
  k_wxt<<<dim3(96, 4), dim3(32, 8), 0, stream>>>(Wx1, WXT);
  k_gx1<<<dim3(160, 48), dim3(256), 0, stream>>>(Xg, WXT, bx1, GX1);
  hipFuncSetAttribute((const void*)k_main, hipFuncAttributeMaxDynamicSharedMemorySize, LDS_BYTES);
  k_main<<<dim3(NB), dim3(NT), LDS_BYTES, stream>>>(WT, GX1, h0b, h1b, cnt,
                                                    bh1, bx2, bh2, Wf, bfp, (float*)d_out);
}